// Round 1
// baseline (1029.368 us; speedup 1.0000x reference)
//
#include <hip/hip_runtime.h>
#include <stdint.h>

#define NB 16
#define TQ 1369
#define TS 5476
#define DD 768

#define BM 128
#define BN 128
#define BK 32
#define LDP 40   // LDS row stride in bf16 elems (80 B = 5*16 B -> 2-way-free b64 banks)

typedef float f32x4 __attribute__((ext_vector_type(4)));
typedef short short8 __attribute__((ext_vector_type(8)));

// ---------- helpers ----------

__device__ inline float waveReduceSum(float v) {
    #pragma unroll
    for (int m = 32; m >= 1; m >>= 1) v += __shfl_xor(v, m);
    return v;
}

// pack high-16s of two fp32 -> one dword: [a.hi16 : b.hi16] (b is element k-even -> low half)
__device__ inline unsigned perm_hi16(unsigned a, unsigned b) {
    return __builtin_amdgcn_perm(a, b, 0x07060302u);
}

// residual (x - trunc_bf16(x)) rounded-to-bf16 bits (pre-shift; take hi16 via perm)
__device__ inline unsigned lo_rb(float x) {
    unsigned xb = __float_as_uint(x);
    float hi = __uint_as_float(xb & 0xFFFF0000u);
    return __float_as_uint(x - hi) + 0x8000u;   // half-up rounding of bf16 trunc
}

// convert 8 consecutive-K fp32 (a.x..a.w, b.x..b.w) into bf16 hi/lo and store to LDS
__device__ inline void cvt_store8(unsigned short* ph, unsigned short* pl, float4 a, float4 b) {
    unsigned ax = __float_as_uint(a.x), ay = __float_as_uint(a.y);
    unsigned az = __float_as_uint(a.z), aw = __float_as_uint(a.w);
    unsigned bx = __float_as_uint(b.x), by = __float_as_uint(b.y);
    unsigned bz = __float_as_uint(b.z), bw = __float_as_uint(b.w);
    uint2 h0, h1, l0, l1;
    h0.x = perm_hi16(ay, ax); h0.y = perm_hi16(aw, az);
    h1.x = perm_hi16(by, bx); h1.y = perm_hi16(bw, bz);
    l0.x = perm_hi16(lo_rb(a.y), lo_rb(a.x)); l0.y = perm_hi16(lo_rb(a.w), lo_rb(a.z));
    l1.x = perm_hi16(lo_rb(b.y), lo_rb(b.x)); l1.y = perm_hi16(lo_rb(b.w), lo_rb(b.z));
    *(uint2*)ph       = h0;  *(uint2*)(ph + 4) = h1;
    *(uint2*)pl       = l0;  *(uint2*)(pl + 4) = l1;
}

__device__ inline short8 load_frag(const unsigned short* p) {
    union { uint2 u2[2]; short8 s; } u;
    u.u2[0] = *(const uint2*)p;
    u.u2[1] = *(const uint2*)(p + 4);
    return u.s;
}

__device__ inline f32x4 mfma16(short8 a, short8 b, f32x4 c) {
    return __builtin_amdgcn_mfma_f32_16x16x32_bf16(a, b, c, 0, 0, 0);
}

// ---------- kernel 1: cls = l2norm(mean over shots) ----------

__global__ __launch_bounds__(256) void cls_kernel(const float* __restrict__ xc,
                                                  float* __restrict__ cls) {
    int n = blockIdx.x, tid = threadIdx.x;
    const float* base = xc + (size_t)n * 4 * DD;
    float v[3]; float ss = 0.f;
    #pragma unroll
    for (int i = 0; i < 3; i++) {
        int e = tid + i * 256;
        float a = base[e] + base[DD + e] + base[2 * DD + e] + base[3 * DD + e];
        v[i] = a * 0.25f; ss += v[i] * v[i];
    }
    ss = waveReduceSum(ss);
    __shared__ float red[4]; __shared__ float rn;
    if ((tid & 63) == 0) red[tid >> 6] = ss;
    __syncthreads();
    if (tid == 0) {
        float t = red[0] + red[1] + red[2] + red[3];
        rn = 1.0f / fmaxf(sqrtf(t), 1e-12f);
    }
    __syncthreads();
    float r = rn;
    #pragma unroll
    for (int i = 0; i < 3; i++) cls[(size_t)n * DD + tid + i * 256] = v[i] * r;
}

// ---------- kernel 2: reciprocal row norms for q and s ----------

__global__ __launch_bounds__(256) void rnorm_kernel(const float* __restrict__ Q,
                                                    const float* __restrict__ S,
                                                    float* __restrict__ rq,
                                                    float* __restrict__ rs) {
    int wid = (int)((blockIdx.x * 256u + threadIdx.x) >> 6);
    int lane = threadIdx.x & 63;
    const int NQ = NB * TQ, NSr = NB * TS;
    if (wid >= NQ + NSr) return;
    const float* base = (wid < NQ) ? Q + (size_t)wid * DD
                                   : S + (size_t)(wid - NQ) * DD;
    float ss = 0.f;
    #pragma unroll
    for (int i = 0; i < 3; i++) {
        float4 x = ((const float4*)base)[lane + i * 64];
        ss += x.x * x.x + x.y * x.y + x.z * x.z + x.w * x.w;
    }
    ss = waveReduceSum(ss);
    if (lane == 0) {
        float r = 1.0f / fmaxf(sqrtf(ss), 1e-12f);
        if (wid < NQ) rq[wid] = r; else rs[wid - NQ] = r;
    }
}

// ---------- kernel 3: split-bf16 GEMM + fused min/argmin ----------

__global__ __launch_bounds__(256, 3) void gemm_kernel(const float* __restrict__ Q,
                                                      const float* __restrict__ S,
                                                      const float* __restrict__ rq,
                                                      const float* __restrict__ rs,
                                                      unsigned long long* __restrict__ best) {
    __shared__ __align__(16) unsigned short Ah[BM * LDP];
    __shared__ __align__(16) unsigned short Al[BM * LDP];
    __shared__ __align__(16) unsigned short Bh[BN * LDP];
    __shared__ __align__(16) unsigned short Bl[BN * LDP];

    int tid = threadIdx.x;
    int bx = blockIdx.x, by = blockIdx.y, n = blockIdx.z;
    const float* Abase = Q + (size_t)n * TQ * DD;
    const float* Bbase = S + (size_t)n * TS * DD;

    int w = tid >> 6, lane = tid & 63;
    int wm = w & 1, wn = w >> 1;
    int g = lane >> 4, c16 = lane & 15;

    f32x4 acc[4][4] = {};

    const int arow0 = bx * BM, brow0 = by * BN;

    for (int kt = 0; kt < DD; kt += BK) {
        __syncthreads();   // previous iteration's LDS reads done
        #pragma unroll
        for (int half = 0; half < 2; half++) {
            int c = tid + half * 256;          // chunk id 0..511
            int row = c >> 2, cc = c & 3;      // 8-elem K-chunk cc within BK
            {
                int grow = min(arow0 + row, TQ - 1);
                const float* p = Abase + (size_t)grow * DD + kt + cc * 8;
                float4 x0 = *(const float4*)p;
                float4 x1 = *(const float4*)(p + 4);
                cvt_store8(&Ah[row * LDP + cc * 8], &Al[row * LDP + cc * 8], x0, x1);
            }
            {
                int grow = min(brow0 + row, TS - 1);
                const float* p = Bbase + (size_t)grow * DD + kt + cc * 8;
                float4 x0 = *(const float4*)p;
                float4 x1 = *(const float4*)(p + 4);
                cvt_store8(&Bh[row * LDP + cc * 8], &Bl[row * LDP + cc * 8], x0, x1);
            }
        }
        __syncthreads();

        short8 ah[4], al[4], bh[4], bl[4];
        #pragma unroll
        for (int i = 0; i < 4; i++) {
            int ar = wm * 64 + i * 16 + c16;
            ah[i] = load_frag(&Ah[ar * LDP + g * 8]);
            al[i] = load_frag(&Al[ar * LDP + g * 8]);
            int br = wn * 64 + i * 16 + c16;
            bh[i] = load_frag(&Bh[br * LDP + g * 8]);
            bl[i] = load_frag(&Bl[br * LDP + g * 8]);
        }
        #pragma unroll
        for (int mi = 0; mi < 4; mi++)
            #pragma unroll
            for (int ni = 0; ni < 4; ni++) {
                acc[mi][ni] = mfma16(ah[mi], bh[ni], acc[mi][ni]);   // hi*hi
                acc[mi][ni] = mfma16(ah[mi], bl[ni], acc[mi][ni]);   // hi*lo
                acc[mi][ni] = mfma16(al[mi], bh[ni], acc[mi][ni]);   // lo*hi
            }
    }

    // ---- epilogue: d = 1 - rq*rs*dot ; row-wise min+argmin ; atomicMin packed ----
    float rsv[4]; int cols[4];
    #pragma unroll
    for (int ni = 0; ni < 4; ni++) {
        int col = brow0 + wn * 64 + ni * 16 + c16;
        cols[ni] = col;
        rsv[ni] = (col < TS) ? rs[(size_t)n * TS + col] : 0.f;
    }
    const float* rqn = rq + (size_t)n * TQ;
    unsigned long long* bestn = best + (size_t)n * TQ;

    #pragma unroll
    for (int mi = 0; mi < 4; mi++) {
        int rowb = arow0 + wm * 64 + mi * 16 + g * 4;   // row of reg r = rowb + r
        float rq4[4];
        #pragma unroll
        for (int r = 0; r < 4; r++) {
            int qr = rowb + r;
            rq4[r] = (qr < TQ) ? rqn[qr] : 0.f;
        }
        #pragma unroll
        for (int r = 0; r < 4; r++) {
            float dv = 1e30f; int di = 0x7FFFFFFF;
            #pragma unroll
            for (int ni = 0; ni < 4; ni++) {
                float m = acc[mi][ni][r] * rsv[ni];
                float d = 1.0f - rq4[r] * m;
                float dd = (cols[ni] < TS) ? d : 1e30f;
                int ii = cols[ni];
                if (dd < dv || (dd == dv && ii < di)) { dv = dd; di = ii; }
            }
            // reduce across the 16 columns held by the lane group (low 4 lane bits)
            #pragma unroll
            for (int mbit = 1; mbit < 16; mbit <<= 1) {
                float od = __shfl_xor(dv, mbit);
                int   oi = __shfl_xor(di, mbit);
                if (od < dv || (od == dv && oi < di)) { dv = od; di = oi; }
            }
            if (c16 == 0 && (rowb + r) < TQ) {
                unsigned u = __float_as_uint(dv);
                unsigned key = (u & 0x80000000u) ? ~u : (u | 0x80000000u);
                unsigned long long pk = ((unsigned long long)key << 32) | (unsigned)di;
                atomicMin(&bestn[rowb + r], pk);
            }
        }
    }
}

// ---------- kernel 4: head (gather nearest, linear + sigmoid, write outputs) ----------

__global__ __launch_bounds__(256) void head_kernel(const float* __restrict__ Q,
                                                   const float* __restrict__ S,
                                                   const float* __restrict__ rq,
                                                   const float* __restrict__ rs,
                                                   const float* __restrict__ cls,
                                                   const float* __restrict__ W,
                                                   const float* __restrict__ bb,
                                                   const unsigned long long* __restrict__ best,
                                                   float* __restrict__ out) {
    int wid = (int)((blockIdx.x * 256u + threadIdx.x) >> 6);
    int lane = threadIdx.x & 63;
    if (wid >= NB * TQ) return;
    int n = wid / TQ;
    unsigned long long pk = best[wid];
    unsigned key = (unsigned)(pk >> 32);
    int idx = (int)(unsigned)(pk & 0xFFFFFFFFu);
    unsigned ub = (key & 0x80000000u) ? (key ^ 0x80000000u) : ~key;
    float dmin = __uint_as_float(ub);

    const float* qrow = Q + (size_t)wid * DD;
    const float* srow = S + ((size_t)n * TS + idx) * DD;
    const float* clsr = cls + (size_t)n * DD;
    float sq = 0.f, ssum = 0.f, sc = 0.f;
    #pragma unroll
    for (int i = 0; i < 12; i++) {
        int j = lane + i * 64;
        sq   += qrow[j] * W[j];
        ssum += srow[j] * W[DD + j];
        sc   += clsr[j] * W[2 * DD + j];
    }
    float tot = sq * rq[wid] + ssum * rs[(size_t)n * TS + idx] + sc;
    tot = waveReduceSum(tot);
    if (lane == 0) {
        float logit = tot + bb[0];
        float pred = 1.0f / (1.0f + expf(-logit));
        out[wid] = pred * dmin;
        out[NB * TQ + wid] = pred;
    }
}

// ---------- launch ----------

extern "C" void kernel_launch(void* const* d_in, const int* in_sizes, int n_in,
                              void* d_out, int out_size, void* d_ws, size_t ws_size,
                              hipStream_t stream) {
    const float* Q  = (const float*)d_in[0];
    const float* S  = (const float*)d_in[1];
    const float* XC = (const float*)d_in[2];
    const float* W  = (const float*)d_in[3];
    const float* B  = (const float*)d_in[4];
    (void)in_sizes; (void)n_in; (void)out_size; (void)ws_size;

    char* ws = (char*)d_ws;
    unsigned long long* best = (unsigned long long*)ws;      // 16*1369*8  = 175232 B
    float* rq  = (float*)(ws + 175232);                       // 16*1369*4 =  87616 B
    float* rs  = (float*)(ws + 262848);                       // 16*5476*4 = 350464 B
    float* cls = (float*)(ws + 613312);                       // 16*768*4  =  49152 B

    hipMemsetAsync(best, 0xFF, (size_t)NB * TQ * 8, stream);  // +inf sentinel for packed atomicMin

    cls_kernel<<<NB, 256, 0, stream>>>(XC, cls);

    int rn_rows = NB * TQ + NB * TS;                           // 109520 (divisible by 4)
    rnorm_kernel<<<rn_rows / 4, 256, 0, stream>>>(Q, S, rq, rs);

    dim3 grid((TQ + BM - 1) / BM, (TS + BN - 1) / BN, NB);     // (11, 43, 16)
    gemm_kernel<<<grid, 256, 0, stream>>>(Q, S, rq, rs, best);

    head_kernel<<<(NB * TQ) / 4, 256, 0, stream>>>(Q, S, rq, rs, cls, W, B, best, (float*)d_out);
}